// Round 5
// baseline (220.667 us; speedup 1.0000x reference)
//
#include <hip/hip_runtime.h>
#include <hip/hip_bf16.h>
#include <stdint.h>

#define B_ 32
#define S_ 8192
#define HD_ 256
#define HE_ 256
#define CHUNK 256
#define ROWS 32              /* rows per step */
#define MSTEPS (CHUNK/ROWS)  /* 8 steps */
#define NCHUNK (S_/CHUNK)    /* 32 chunks per batch */

typedef __attribute__((ext_vector_type(8))) short bf16x8;
typedef __attribute__((ext_vector_type(4))) float f32x4;

__device__ __forceinline__ unsigned short f2bf(float f) {
  uint32_t u = __float_as_uint(f);
  u += 0x7FFFu + ((u >> 16) & 1u);          // round-to-nearest-even
  return (unsigned short)(u >> 16);
}
__device__ __forceinline__ float bf2f(unsigned short h) {
  return __uint_as_float(((uint32_t)h) << 16);
}
__device__ __forceinline__ float tanh_fast(float x) {
  // tanh(x) = 1 - 2/(exp(2x)+1); well-behaved at +/-inf, no NaN
  float e = __expf(2.0f * x);
  return 1.0f - 2.0f * __builtin_amdgcn_rcpf(e + 1.0f);
}

// ---------------- prep: qv[b,h] = q@Wa^T + Wa_b + Ua_b ; Ua -> bf16 ----------------
__global__ void prep_kernel(const float* __restrict__ query,
                            const float* __restrict__ Wa_w,
                            const float* __restrict__ Wa_b,
                            const float* __restrict__ Ua_w,
                            const float* __restrict__ Ua_b,
                            float* __restrict__ qv,
                            unsigned short* __restrict__ ua_bf) {
  const int blk = blockIdx.x, t = threadIdx.x;
  if (blk < B_) {
    __shared__ float qs[HD_];
    qs[t] = query[blk * HD_ + t];
    __syncthreads();
    const float* wr = Wa_w + (size_t)t * HD_;
    float s = Wa_b[t] + Ua_b[t];
#pragma unroll 8
    for (int d = 0; d < HD_; ++d) s += qs[d] * wr[d];
    qv[blk * HD_ + t] = s;
  } else {
    const int base = (blk - B_) * 2048 + t * 8;
    float4 v0 = *(const float4*)(Ua_w + base);
    float4 v1 = *(const float4*)(Ua_w + base + 4);
    uint4 pk;
    pk.x = (uint32_t)f2bf(v0.x) | ((uint32_t)f2bf(v0.y) << 16);
    pk.y = (uint32_t)f2bf(v0.z) | ((uint32_t)f2bf(v0.w) << 16);
    pk.z = (uint32_t)f2bf(v1.x) | ((uint32_t)f2bf(v1.y) << 16);
    pk.w = (uint32_t)f2bf(v1.z) | ((uint32_t)f2bf(v1.w) << 16);
    *(uint4*)(ua_bf + base) = pk;
  }
}

// ---------------- main: fused k_proj GEMM + tanh + score-exp + context partial ----------------
// 512 threads = 8 waves. Wave w owns h-slice [32w,32w+32) with Ua frags in regs (read once).
// 32-row steps, triple-buffered bf16 LDS tiles, numerator lagged one step (runs in
// compute phase), 2 barriers per step. Keys touch HBM exactly once.
__global__ __launch_bounds__(512)
__attribute__((amdgpu_waves_per_eu(4, 4)))
void main_kernel(const float* __restrict__ keys,
                 const float* __restrict__ qv,
                 const float* __restrict__ Va_w,
                 const unsigned short* __restrict__ ua_bf,
                 float* __restrict__ wexp_g,
                 float* __restrict__ partials) {
  __shared__ __align__(16) char kt[3 * ROWS * 512];   // 3 x (32 rows x 512B bf16), swizzled
  __shared__ float sc[ROWS][9];                        // per-row, per-wave score partials
  __shared__ float swp[ROWS];                          // per-row exp(score)
  __shared__ float num2[512];

  const int t = threadIdx.x;
  const int b = blockIdx.y;
  const int chunk = blockIdx.x;
  const int s0 = chunk * CHUNK;
  const int lane = t & 63;
  const int w = t >> 6;
  const int ln = lane & 15;
  const int hi = lane >> 4;

  // ---- B fragments: wave w's 32 h-cols, 2 h-tiles, read ONCE (64 VGPRs) ----
  const unsigned short* ub0 = ua_bf + (size_t)(w * 32 + ln) * HE_ + hi * 8;
  const unsigned short* ub1 = ub0 + 16 * HE_;
  bf16x8 bb0[8], bb1[8];
#pragma unroll
  for (int k = 0; k < 8; ++k) {
    bb0[k] = *(const bf16x8*)(ub0 + k * 32);
    bb1[k] = *(const bf16x8*)(ub1 + k * 32);
  }
  const float q0  = qv[b * HD_ + w * 32 + ln];
  const float q1  = qv[b * HD_ + w * 32 + 16 + ln];
  const float va0 = Va_w[w * 32 + ln];
  const float va1 = Va_w[w * 32 + 16 + ln];

  // ---- staging geometry: thread t handles rows (t>>5) and (t>>5)+16, chunk t&31 ----
  const int srow = t >> 5;            // 0..15
  const int scch = t & 31;            // 16B bf16 chunk within 512B row
  const float* ksrcA = keys + ((size_t)b * S_ + s0 + srow) * HE_ + scch * 8;
  const float* ksrcB = ksrcA + 16 * HE_;
  const int ldsoffA = srow * 512 + ((scch * 16) ^ ((srow & 7) << 4));
  const int ldsoffB = ldsoffA + 16 * 512;   // (srow+16)&7 == srow&7

  // ---- prologue: stage step 0 into buffer 0 ----
  {
    float4 a0 = *(const float4*)(ksrcA);
    float4 a1 = *(const float4*)(ksrcA + 4);
    float4 b0 = *(const float4*)(ksrcB);
    float4 b1 = *(const float4*)(ksrcB + 4);
    uint4 pk;
    pk.x = (uint32_t)f2bf(a0.x) | ((uint32_t)f2bf(a0.y) << 16);
    pk.y = (uint32_t)f2bf(a0.z) | ((uint32_t)f2bf(a0.w) << 16);
    pk.z = (uint32_t)f2bf(a1.x) | ((uint32_t)f2bf(a1.y) << 16);
    pk.w = (uint32_t)f2bf(a1.z) | ((uint32_t)f2bf(a1.w) << 16);
    *(uint4*)(kt + ldsoffA) = pk;
    pk.x = (uint32_t)f2bf(b0.x) | ((uint32_t)f2bf(b0.y) << 16);
    pk.y = (uint32_t)f2bf(b0.z) | ((uint32_t)f2bf(b0.w) << 16);
    pk.z = (uint32_t)f2bf(b1.x) | ((uint32_t)f2bf(b1.y) << 16);
    pk.w = (uint32_t)f2bf(b1.z) | ((uint32_t)f2bf(b1.w) << 16);
    *(uint4*)(kt + ldsoffB) = pk;
  }
  __syncthreads();

  const int half = t >> 8;            // numerator row-half (0/1)
  const int e2 = (t & 255) * 2;       // numerator column byte offset (bf16)
  const int asw = (ln & 7) << 4;      // A-frag row swizzle
  float num = 0.f;

  for (int i = 0; i < MSTEPS; ++i) {
    char* cur  = kt + (i % 3) * (ROWS * 512);
    char* nxt  = kt + ((i + 1) % 3) * (ROWS * 512);
    char* prev = kt + ((i + 2) % 3) * (ROWS * 512);

    // issue next-step global loads early (T14: issue-early / write-late)
    float4 ga0, ga1, gb0, gb1;
    if (i + 1 < MSTEPS) {
      const float* kA = ksrcA + (size_t)(i + 1) * ROWS * HE_;
      const float* kB = ksrcB + (size_t)(i + 1) * ROWS * HE_;
      ga0 = *(const float4*)(kA);
      ga1 = *(const float4*)(kA + 4);
      gb0 = *(const float4*)(kB);
      gb1 = *(const float4*)(kB + 4);
    }

    // ---- MFMA: 2 M-subtiles x 2 h-tiles; A-frags just-in-time from LDS ----
    f32x4 a00 = {0.f,0.f,0.f,0.f}, a01 = {0.f,0.f,0.f,0.f};
    f32x4 a10 = {0.f,0.f,0.f,0.f}, a11 = {0.f,0.f,0.f,0.f};
    const char* arow0 = cur + ln * 512;
    const char* arow1 = cur + (16 + ln) * 512;
#pragma unroll
    for (int k = 0; k < 8; ++k) {
      const int ko = (k * 64 + hi * 16) ^ asw;
      bf16x8 af0 = *(const bf16x8*)(arow0 + ko);
      bf16x8 af1 = *(const bf16x8*)(arow1 + ko);
      a00 = __builtin_amdgcn_mfma_f32_16x16x32_bf16(af0, bb0[k], a00, 0, 0, 0);
      a01 = __builtin_amdgcn_mfma_f32_16x16x32_bf16(af0, bb1[k], a01, 0, 0, 0);
      a10 = __builtin_amdgcn_mfma_f32_16x16x32_bf16(af1, bb0[k], a10, 0, 0, 0);
      a11 = __builtin_amdgcn_mfma_f32_16x16x32_bf16(af1, bb1[k], a11, 0, 0, 0);
    }

    // ---- per-row partial over this wave's 32 h-cols ----
#pragma unroll
    for (int r = 0; r < 4; ++r) {
      float v0 = tanh_fast(a00[r] + q0) * va0 + tanh_fast(a01[r] + q1) * va1;
      float v1 = tanh_fast(a10[r] + q0) * va0 + tanh_fast(a11[r] + q1) * va1;
      v0 += __shfl_xor(v0, 1, 64);
      v0 += __shfl_xor(v0, 2, 64);
      v0 += __shfl_xor(v0, 4, 64);
      v0 += __shfl_xor(v0, 8, 64);
      v1 += __shfl_xor(v1, 1, 64);
      v1 += __shfl_xor(v1, 2, 64);
      v1 += __shfl_xor(v1, 4, 64);
      v1 += __shfl_xor(v1, 8, 64);
      if (ln == 0) {
        sc[hi * 4 + r][w] = v0;
        sc[16 + hi * 4 + r][w] = v1;
      }
    }

    // ---- lagged context numerator for tile i-1 (swp + prev both ready) ----
    if (i > 0) {
#pragma unroll
      for (int rr = 0; rr < 16; ++rr) {
        const int row = half * 16 + rr;
        unsigned short kv = *(const unsigned short*)(prev + row * 512 + (e2 ^ ((row & 7) << 4)));
        num += swp[row] * bf2f(kv);
      }
    }

    // ---- stage-write next tile ----
    if (i + 1 < MSTEPS) {
      uint4 pk;
      pk.x = (uint32_t)f2bf(ga0.x) | ((uint32_t)f2bf(ga0.y) << 16);
      pk.y = (uint32_t)f2bf(ga0.z) | ((uint32_t)f2bf(ga0.w) << 16);
      pk.z = (uint32_t)f2bf(ga1.x) | ((uint32_t)f2bf(ga1.y) << 16);
      pk.w = (uint32_t)f2bf(ga1.z) | ((uint32_t)f2bf(ga1.w) << 16);
      *(uint4*)(nxt + ldsoffA) = pk;
      pk.x = (uint32_t)f2bf(gb0.x) | ((uint32_t)f2bf(gb0.y) << 16);
      pk.y = (uint32_t)f2bf(gb0.z) | ((uint32_t)f2bf(gb0.w) << 16);
      pk.z = (uint32_t)f2bf(gb1.x) | ((uint32_t)f2bf(gb1.y) << 16);
      pk.w = (uint32_t)f2bf(gb1.z) | ((uint32_t)f2bf(gb1.w) << 16);
      *(uint4*)(nxt + ldsoffB) = pk;
    }
    __syncthreads();

    // ---- row score = sum over 8 waves; exp (no max shift: scores bounded) ----
    if (t < ROWS) {
      float s = sc[t][0];
#pragma unroll
      for (int ww = 1; ww < 8; ++ww) s += sc[t][ww];
      float e = __expf(s);
      swp[t] = e;
      wexp_g[(size_t)b * S_ + s0 + i * ROWS + t] = e;
    }
    __syncthreads();
  }

  // ---- epilogue: numerator for last tile ----
  {
    const char* prev = kt + ((MSTEPS - 1) % 3) * (ROWS * 512);
#pragma unroll
    for (int rr = 0; rr < 16; ++rr) {
      const int row = half * 16 + rr;
      unsigned short kv = *(const unsigned short*)(prev + row * 512 + (e2 ^ ((row & 7) << 4)));
      num += swp[row] * bf2f(kv);
    }
  }

  num2[t] = num;
  __syncthreads();
  if (t < 256) {
    partials[((size_t)b * NCHUNK + chunk) * 256 + t] = num2[t] + num2[t + 256];
  }
}

// ---------------- combine: den + context + weights per batch ----------------
__global__ void combine_kernel(const float* __restrict__ wexp_g,
                               const float* __restrict__ partials,
                               float* __restrict__ out) {
  __shared__ float red[4];
  __shared__ float rdsh;
  const int b = blockIdx.x, t = threadIdx.x;   // 256 threads
  const float* we = wexp_g + (size_t)b * S_;
  float s = 0.f;
#pragma unroll 4
  for (int i = t; i < S_; i += 256) s += we[i];
#pragma unroll
  for (int mm = 32; mm; mm >>= 1) s += __shfl_xor(s, mm, 64);
  if ((t & 63) == 0) red[t >> 6] = s;
  __syncthreads();
  if (t == 0) rdsh = 1.0f / (red[0] + red[1] + red[2] + red[3]);
  __syncthreads();
  const float rd = rdsh;

  const float* pb = partials + (size_t)b * NCHUNK * 256;
  float num = 0.f;
#pragma unroll 4
  for (int i = 0; i < NCHUNK; ++i) num += pb[i * 256 + t];
  out[b * HE_ + t] = num * rd;

  float* wout = out + B_ * HE_ + (size_t)b * S_;
#pragma unroll 4
  for (int i = t; i < S_; i += 256) wout[i] = we[i] * rd;
}

extern "C" void kernel_launch(void* const* d_in, const int* in_sizes, int n_in,
                              void* d_out, int out_size, void* d_ws, size_t ws_size,
                              hipStream_t stream) {
  const float* query = (const float*)d_in[0];
  const float* keys  = (const float*)d_in[1];
  const float* Wa_w  = (const float*)d_in[2];
  const float* Wa_b  = (const float*)d_in[3];
  const float* Ua_w  = (const float*)d_in[4];
  const float* Ua_b  = (const float*)d_in[5];
  const float* Va_w  = (const float*)d_in[6];
  // Va_b (d_in[7]) is a constant score shift: softmax-invariant, dropped.
  float* out = (float*)d_out;

  char* ws = (char*)d_ws;
  float* qv             = (float*)ws;                               // 32 KB
  unsigned short* ua_bf = (unsigned short*)(ws + 32 * 1024);        // 128 KB
  float* wexp_g         = (float*)(ws + 160 * 1024);                // 1 MB
  float* partials       = (float*)(ws + 160 * 1024 + 1048576);      // 1 MB

  prep_kernel<<<64, 256, 0, stream>>>(query, Wa_w, Wa_b, Ua_w, Ua_b, qv, ua_bf);
  dim3 g(NCHUNK, B_);
  main_kernel<<<g, 512, 0, stream>>>(keys, qv, Va_w, ua_bf, wexp_g, partials);
  combine_kernel<<<B_, 256, 0, stream>>>(wexp_g, partials, out);
}

// Round 6
// 130.706 us; speedup vs baseline: 1.6883x; 1.6883x over previous
//
#include <hip/hip_runtime.h>
#include <hip/hip_bf16.h>
#include <stdint.h>

#define B_ 32
#define S_ 8192
#define HD_ 256
#define HE_ 256
#define CHUNK 256
#define ROWS 16              /* rows per step */
#define MSTEPS (CHUNK/ROWS)  /* 16 steps */
#define NCHUNK (S_/CHUNK)    /* 32 chunks per batch */

typedef __attribute__((ext_vector_type(8))) short bf16x8;
typedef __attribute__((ext_vector_type(4))) float f32x4;

__device__ __forceinline__ unsigned short f2bf(float f) {
  uint32_t u = __float_as_uint(f);
  u += 0x7FFFu + ((u >> 16) & 1u);          // round-to-nearest-even
  return (unsigned short)(u >> 16);
}
__device__ __forceinline__ float bf2f(unsigned short h) {
  return __uint_as_float(((uint32_t)h) << 16);
}
__device__ __forceinline__ float tanh_fast(float x) {
  // tanh(x) = 1 - 2/(exp(2x)+1); well-behaved at +/-inf, no NaN
  float e = __expf(2.0f * x);
  return 1.0f - 2.0f * __builtin_amdgcn_rcpf(e + 1.0f);
}

// ---------------- prep: qv[b,h] = q@Wa^T + Wa_b + Ua_b ; Ua -> bf16 ----------------
__global__ void prep_kernel(const float* __restrict__ query,
                            const float* __restrict__ Wa_w,
                            const float* __restrict__ Wa_b,
                            const float* __restrict__ Ua_w,
                            const float* __restrict__ Ua_b,
                            float* __restrict__ qv,
                            unsigned short* __restrict__ ua_bf) {
  const int blk = blockIdx.x, t = threadIdx.x;
  if (blk < B_) {
    __shared__ float qs[HD_];
    qs[t] = query[blk * HD_ + t];
    __syncthreads();
    const float* wr = Wa_w + (size_t)t * HD_;
    float s = Wa_b[t] + Ua_b[t];
#pragma unroll 8
    for (int d = 0; d < HD_; ++d) s += qs[d] * wr[d];
    qv[blk * HD_ + t] = s;
  } else {
    const int base = (blk - B_) * 2048 + t * 8;
    float4 v0 = *(const float4*)(Ua_w + base);
    float4 v1 = *(const float4*)(Ua_w + base + 4);
    uint4 pk;
    pk.x = (uint32_t)f2bf(v0.x) | ((uint32_t)f2bf(v0.y) << 16);
    pk.y = (uint32_t)f2bf(v0.z) | ((uint32_t)f2bf(v0.w) << 16);
    pk.z = (uint32_t)f2bf(v1.x) | ((uint32_t)f2bf(v1.y) << 16);
    pk.w = (uint32_t)f2bf(v1.z) | ((uint32_t)f2bf(v1.w) << 16);
    *(uint4*)(ua_bf + base) = pk;
  }
}

// ---------------- main: fused k_proj GEMM + tanh + score-exp + context partial ----------------
// 512 threads = 8 waves. Wave w owns h-slice [32w,32w+32) with Ua frags in regs (read once,
// expected in AGPR half of the unified file). 16-row M-steps, triple-buffered bf16 LDS
// tiles, numerator lagged one step (runs inside compute phase), 2 barriers per step.
// Register budget: bb 64 (AGPR) + acc 8 + early-issue 8 + misc ~30 <= 128/wave at 4 waves/EU.
__global__ __launch_bounds__(512)
__attribute__((amdgpu_waves_per_eu(4, 4)))
void main_kernel(const float* __restrict__ keys,
                 const float* __restrict__ qv,
                 const float* __restrict__ Va_w,
                 const unsigned short* __restrict__ ua_bf,
                 float* __restrict__ wexp_g,
                 float* __restrict__ partials) {
  __shared__ __align__(16) char kt[3 * ROWS * 512];   // 3 x (16 rows x 512B bf16), swizzled
  __shared__ float sc[ROWS][9];                        // per-row, per-wave score partials
  __shared__ float swp[ROWS];                          // per-row exp(score)
  __shared__ float num2[512];

  const int t = threadIdx.x;
  const int b = blockIdx.y;
  const int chunk = blockIdx.x;
  const int s0 = chunk * CHUNK;
  const int lane = t & 63;
  const int w = t >> 6;
  const int ln = lane & 15;
  const int hi = lane >> 4;

  // ---- B fragments: wave w's 32 h-cols, 2 h-tiles, read ONCE (64 regs) ----
  const unsigned short* ub0 = ua_bf + (size_t)(w * 32 + ln) * HE_ + hi * 8;
  const unsigned short* ub1 = ub0 + 16 * HE_;
  bf16x8 bb0[8], bb1[8];
#pragma unroll
  for (int k = 0; k < 8; ++k) {
    bb0[k] = *(const bf16x8*)(ub0 + k * 32);
    bb1[k] = *(const bf16x8*)(ub1 + k * 32);
  }
  const float q0  = qv[b * HD_ + w * 32 + ln];
  const float q1  = qv[b * HD_ + w * 32 + 16 + ln];
  const float va0 = Va_w[w * 32 + ln];
  const float va1 = Va_w[w * 32 + 16 + ln];

  // ---- staging geometry: thread t handles row t>>5, 16B bf16 chunk t&31 ----
  const int srow = t >> 5;            // 0..15
  const int scch = t & 31;            // 16B bf16 chunk within 512B row
  const float* ksrc = keys + ((size_t)b * S_ + s0 + srow) * HE_ + scch * 8;
  const int ldsoff = srow * 512 + ((scch * 16) ^ ((srow & 7) << 4));

  // ---- prologue: stage step 0 into buffer 0 ----
  {
    float4 a0 = *(const float4*)(ksrc);
    float4 a1 = *(const float4*)(ksrc + 4);
    uint4 pk;
    pk.x = (uint32_t)f2bf(a0.x) | ((uint32_t)f2bf(a0.y) << 16);
    pk.y = (uint32_t)f2bf(a0.z) | ((uint32_t)f2bf(a0.w) << 16);
    pk.z = (uint32_t)f2bf(a1.x) | ((uint32_t)f2bf(a1.y) << 16);
    pk.w = (uint32_t)f2bf(a1.z) | ((uint32_t)f2bf(a1.w) << 16);
    *(uint4*)(kt + ldsoff) = pk;
  }
  __syncthreads();

  const int half = t >> 8;            // numerator row-half (0/1)
  const int e2 = (t & 255) * 2;       // numerator column byte offset (bf16)
  const int asw = (ln & 7) << 4;      // A-frag row swizzle
  float num = 0.f;

  for (int i = 0; i < MSTEPS; ++i) {
    char* cur  = kt + (i % 3) * (ROWS * 512);
    char* nxt  = kt + ((i + 1) % 3) * (ROWS * 512);
    char* prev = kt + ((i + 2) % 3) * (ROWS * 512);

    // issue next-step global loads early (T14: issue-early / write-late)
    float4 ga0, ga1;
    if (i + 1 < MSTEPS) {
      const float* kA = ksrc + (size_t)(i + 1) * ROWS * HE_;
      ga0 = *(const float4*)(kA);
      ga1 = *(const float4*)(kA + 4);
    }

    // ---- MFMA: 1 M-subtile x 2 h-tiles; A-frags just-in-time from LDS ----
    f32x4 a00 = {0.f,0.f,0.f,0.f}, a01 = {0.f,0.f,0.f,0.f};
    const char* arow = cur + ln * 512;
#pragma unroll
    for (int k = 0; k < 8; ++k) {
      bf16x8 af = *(const bf16x8*)(arow + ((k * 64 + hi * 16) ^ asw));
      a00 = __builtin_amdgcn_mfma_f32_16x16x32_bf16(af, bb0[k], a00, 0, 0, 0);
      a01 = __builtin_amdgcn_mfma_f32_16x16x32_bf16(af, bb1[k], a01, 0, 0, 0);
    }

    // ---- per-row partial over this wave's 32 h-cols ----
#pragma unroll
    for (int r = 0; r < 4; ++r) {
      float v0 = tanh_fast(a00[r] + q0) * va0 + tanh_fast(a01[r] + q1) * va1;
      v0 += __shfl_xor(v0, 1, 64);
      v0 += __shfl_xor(v0, 2, 64);
      v0 += __shfl_xor(v0, 4, 64);
      v0 += __shfl_xor(v0, 8, 64);
      if (ln == 0) sc[hi * 4 + r][w] = v0;
    }

    // ---- lagged context numerator for tile i-1 (swp + prev both ready) ----
    if (i > 0) {
#pragma unroll
      for (int rr = 0; rr < 8; ++rr) {
        const int row = half * 8 + rr;
        unsigned short kv = *(const unsigned short*)(prev + row * 512 + (e2 ^ ((row & 7) << 4)));
        num += swp[row] * bf2f(kv);
      }
    }

    // ---- stage-write next tile ----
    if (i + 1 < MSTEPS) {
      uint4 pk;
      pk.x = (uint32_t)f2bf(ga0.x) | ((uint32_t)f2bf(ga0.y) << 16);
      pk.y = (uint32_t)f2bf(ga0.z) | ((uint32_t)f2bf(ga0.w) << 16);
      pk.z = (uint32_t)f2bf(ga1.x) | ((uint32_t)f2bf(ga1.y) << 16);
      pk.w = (uint32_t)f2bf(ga1.z) | ((uint32_t)f2bf(ga1.w) << 16);
      *(uint4*)(nxt + ldsoff) = pk;
    }
    __syncthreads();

    // ---- row score = sum over 8 waves; exp (no max shift: |score| <= ~8) ----
    if (t < ROWS) {
      float s = sc[t][0];
#pragma unroll
      for (int ww = 1; ww < 8; ++ww) s += sc[t][ww];
      float e = __expf(s);
      swp[t] = e;
      wexp_g[(size_t)b * S_ + s0 + i * ROWS + t] = e;
    }
    __syncthreads();
  }

  // ---- epilogue: numerator for last tile ----
  {
    const char* last = kt + ((MSTEPS - 1) % 3) * (ROWS * 512);
#pragma unroll
    for (int rr = 0; rr < 8; ++rr) {
      const int row = half * 8 + rr;
      unsigned short kv = *(const unsigned short*)(last + row * 512 + (e2 ^ ((row & 7) << 4)));
      num += swp[row] * bf2f(kv);
    }
  }

  num2[t] = num;
  __syncthreads();
  if (t < 256) {
    partials[((size_t)b * NCHUNK + chunk) * 256 + t] = num2[t] + num2[t + 256];
  }
}

// ---------------- combine: den + context + weights per batch ----------------
__global__ void combine_kernel(const float* __restrict__ wexp_g,
                               const float* __restrict__ partials,
                               float* __restrict__ out) {
  __shared__ float red[4];
  __shared__ float rdsh;
  const int b = blockIdx.x, t = threadIdx.x;   // 256 threads
  const float* we = wexp_g + (size_t)b * S_;
  float s = 0.f;
#pragma unroll 4
  for (int i = t; i < S_; i += 256) s += we[i];
#pragma unroll
  for (int mm = 32; mm; mm >>= 1) s += __shfl_xor(s, mm, 64);
  if ((t & 63) == 0) red[t >> 6] = s;
  __syncthreads();
  if (t == 0) rdsh = 1.0f / (red[0] + red[1] + red[2] + red[3]);
  __syncthreads();
  const float rd = rdsh;

  const float* pb = partials + (size_t)b * NCHUNK * 256;
  float num = 0.f;
#pragma unroll 4
  for (int i = 0; i < NCHUNK; ++i) num += pb[i * 256 + t];
  out[b * HE_ + t] = num * rd;

  float* wout = out + B_ * HE_ + (size_t)b * S_;
#pragma unroll 4
  for (int i = t; i < S_; i += 256) wout[i] = we[i] * rd;
}

extern "C" void kernel_launch(void* const* d_in, const int* in_sizes, int n_in,
                              void* d_out, int out_size, void* d_ws, size_t ws_size,
                              hipStream_t stream) {
  const float* query = (const float*)d_in[0];
  const float* keys  = (const float*)d_in[1];
  const float* Wa_w  = (const float*)d_in[2];
  const float* Wa_b  = (const float*)d_in[3];
  const float* Ua_w  = (const float*)d_in[4];
  const float* Ua_b  = (const float*)d_in[5];
  const float* Va_w  = (const float*)d_in[6];
  // Va_b (d_in[7]) is a constant score shift: softmax-invariant, dropped.
  float* out = (float*)d_out;

  char* ws = (char*)d_ws;
  float* qv             = (float*)ws;                               // 32 KB
  unsigned short* ua_bf = (unsigned short*)(ws + 32 * 1024);        // 128 KB
  float* wexp_g         = (float*)(ws + 160 * 1024);                // 1 MB
  float* partials       = (float*)(ws + 160 * 1024 + 1048576);      // 1 MB

  prep_kernel<<<64, 256, 0, stream>>>(query, Wa_w, Wa_b, Ua_w, Ua_b, qv, ua_bf);
  dim3 g(NCHUNK, B_);
  main_kernel<<<g, 512, 0, stream>>>(keys, qv, Va_w, ua_bf, wexp_g, partials);
  combine_kernel<<<B_, 256, 0, stream>>>(wexp_g, partials, out);
}